// Round 1
// baseline (436.430 us; speedup 1.0000x reference)
//
#include <hip/hip_runtime.h>
#include <hip/hip_bf16.h>

// Shapes fixed by the problem: B=8, M=N=4096, C=256.
#define C_DIM 256
#define LDK 264   // padded LDS row (bf16) for [*][256] tiles: 2-way conflicts only
#define LDV 72    // padded LDS row for V^T [256][64] tiles
#define LDP 72    // padded LDS row for per-wave P [16][64]

typedef __attribute__((ext_vector_type(8))) short bf16x8;
typedef __attribute__((ext_vector_type(4))) float f32x4;

__device__ __forceinline__ unsigned short f2bf(float f) {
    union { float f; unsigned u; } v; v.f = f;
    return (unsigned short)((v.u + 0x7fffu + ((v.u >> 16) & 1u)) >> 16);  // RNE
}

// ---------------- K0: weight fp32 -> bf16 (65536 elems per launch) ----------------
__global__ void cvt_w_kernel(const float* __restrict__ w, unsigned short* __restrict__ o) {
    int i = (blockIdx.x * 256 + threadIdx.x) * 4;
    float4 v = *reinterpret_cast<const float4*>(w + i);
    ushort4 b;
    b.x = f2bf(v.x); b.y = f2bf(v.y); b.z = f2bf(v.z); b.w = f2bf(v.w);
    *reinterpret_cast<ushort4*>(o + i) = b;
}

// ---------------- K1: projection out = in @ W^T + b (bf16 out) ----------------
// TRANS=0: row-major out [32768][256]. TRANS=1: out stored [B][C][N] (for V^T).
template<int TRANS>
__global__ __launch_bounds__(256, 2)
void proj_kernel(const float* __restrict__ in, const unsigned short* __restrict__ wbf,
                 const float* __restrict__ bias, unsigned short* __restrict__ out)
{
    __shared__ __align__(16) unsigned short lds_in[64 * LDK];
    const int tid = threadIdx.x;
    const int rowbase = blockIdx.x * 64;

    // stage 64x256 fp32 tile -> bf16 LDS
    #pragma unroll
    for (int i = 0; i < 16; ++i) {
        int e = i * 1024 + tid * 4;
        int r = e >> 8, c = e & 255;
        float4 v = *reinterpret_cast<const float4*>(in + (size_t)(rowbase + r) * C_DIM + c);
        ushort4 b;
        b.x = f2bf(v.x); b.y = f2bf(v.y); b.z = f2bf(v.z); b.w = f2bf(v.w);
        *reinterpret_cast<ushort4*>(&lds_in[r * LDK + c]) = b;
    }
    __syncthreads();

    const int lane = tid & 63, wave = tid >> 6;
    const int lrow = lane & 15, lkq = lane >> 4, lk = lkq * 8;
    const int r0 = wave * 16;

    bf16x8 a[8];
    #pragma unroll
    for (int ks = 0; ks < 8; ++ks)
        a[ks] = *reinterpret_cast<const bf16x8*>(&lds_in[(r0 + lrow) * LDK + ks * 32 + lk]);

    f32x4 acc[16];
    #pragma unroll
    for (int nf = 0; nf < 16; ++nf) acc[nf] = f32x4{0.f, 0.f, 0.f, 0.f};

    // B[k][j] = W[j][k]: lane holds W row (c_out = nf*16 + lrow), contiguous k. L2-resident.
    #pragma unroll
    for (int nf = 0; nf < 16; ++nf) {
        const unsigned short* wrow = wbf + (nf * 16 + lrow) * C_DIM + lk;
        #pragma unroll
        for (int ks = 0; ks < 8; ++ks) {
            bf16x8 b = *reinterpret_cast<const bf16x8*>(wrow + ks * 32);
            acc[nf] = __builtin_amdgcn_mfma_f32_16x16x32_bf16(a[ks], b, acc[nf], 0, 0, 0);
        }
    }

    if (TRANS == 0) {
        #pragma unroll
        for (int nf = 0; nf < 16; ++nf) {
            float bv = bias[nf * 16 + lrow];
            #pragma unroll
            for (int r = 0; r < 4; ++r) {
                int row = rowbase + r0 + lkq * 4 + r;
                out[(size_t)row * C_DIM + nf * 16 + lrow] = f2bf(acc[nf][r] + bv);
            }
        }
    } else {
        // D rows are consecutive n -> pack 4 bf16 per store into [b][c][n]
        int grow = rowbase + r0 + lkq * 4;
        int bb = grow >> 12, n0 = grow & 4095;
        #pragma unroll
        for (int nf = 0; nf < 16; ++nf) {
            float bv = bias[nf * 16 + lrow];
            int c = nf * 16 + lrow;
            ushort4 pk;
            pk.x = f2bf(acc[nf][0] + bv);
            pk.y = f2bf(acc[nf][1] + bv);
            pk.z = f2bf(acc[nf][2] + bv);
            pk.w = f2bf(acc[nf][3] + bv);
            *reinterpret_cast<ushort4*>(out + ((size_t)(bb * C_DIM + c) << 12) + n0) = pk;
        }
    }
}

// ---------------- K2: flash attention ----------------
// grid 256 blocks: batch = bx&7 (one batch per XCD -> K/V L2-resident), mt = bx>>3.
// 512 threads = 8 waves x 16 Q-rows = 128 Q rows per block. 64-row KV tiles.
__global__ __launch_bounds__(512, 2)
void attn_kernel(const unsigned short* __restrict__ qg, const unsigned short* __restrict__ kg,
                 const unsigned short* __restrict__ vtg, unsigned short* __restrict__ hg)
{
    __shared__ __align__(16) unsigned short lds_k[64 * LDK];       // 33.8 KB
    __shared__ __align__(16) unsigned short lds_v[C_DIM * LDV];    // 36.9 KB
    __shared__ __align__(16) unsigned short lds_p[8 * 16 * LDP];   // 18.4 KB

    const int tid = threadIdx.x;
    const int batch = blockIdx.x & 7;
    const int mt = blockIdx.x >> 3;
    const int lane = tid & 63, wave = tid >> 6;
    const int lrow = lane & 15, lkq = lane >> 4, lk = lkq * 8;

    const size_t qrow0 = (size_t)batch * 4096 + mt * 128 + wave * 16;
    const unsigned short* kbase = kg + (size_t)batch * 4096 * C_DIM;
    const unsigned short* vbase = vtg + (size_t)batch * C_DIM * 4096;

    // Q rows held in registers: A[i][k], i=lrow, k contiguous 8 per lane
    bf16x8 qf[8];
    #pragma unroll
    for (int ks = 0; ks < 8; ++ks)
        qf[ks] = *reinterpret_cast<const bf16x8*>(qg + (qrow0 + lrow) * C_DIM + ks * 32 + lk);

    f32x4 o[16];
    #pragma unroll
    for (int nf = 0; nf < 16; ++nf) o[nf] = f32x4{0.f, 0.f, 0.f, 0.f};
    float mrow[4] = {-__builtin_inff(), -__builtin_inff(), -__builtin_inff(), -__builtin_inff()};
    float lsum[4] = {0.f, 0.f, 0.f, 0.f};

    for (int kt = 0; kt < 64; ++kt) {
        const int kv0 = kt * 64;
        // stage K tile [64][256] bf16
        #pragma unroll
        for (int i = 0; i < 4; ++i) {
            int e = i * 4096 + tid * 8;
            int r = e >> 8, c = e & 255;
            uint4 d = *reinterpret_cast<const uint4*>(kbase + (size_t)(kv0 + r) * C_DIM + c);
            *reinterpret_cast<uint4*>(&lds_k[r * LDK + c]) = d;
        }
        // stage V^T tile [256][64] bf16
        #pragma unroll
        for (int i = 0; i < 4; ++i) {
            int e = i * 4096 + tid * 8;
            int r = e >> 6, c = e & 63;
            uint4 d = *reinterpret_cast<const uint4*>(vbase + (size_t)r * 4096 + kv0 + c);
            *reinterpret_cast<uint4*>(&lds_v[r * LDV + c]) = d;
        }
        __syncthreads();

        // S = Q K^T : per wave 16 q-rows x 64 kv-cols
        f32x4 s[4];
        #pragma unroll
        for (int nf = 0; nf < 4; ++nf) {
            s[nf] = f32x4{0.f, 0.f, 0.f, 0.f};
            #pragma unroll
            for (int ks = 0; ks < 8; ++ks) {
                bf16x8 b = *reinterpret_cast<const bf16x8*>(
                    &lds_k[(nf * 16 + lrow) * LDK + ks * 32 + lk]);
                s[nf] = __builtin_amdgcn_mfma_f32_16x16x32_bf16(qf[ks], b, s[nf], 0, 0, 0);
            }
        }

        // online softmax (fp32). row r lives on the 16 lanes with same lkq.
        const float scale = 0.0625f;  // 1/sqrt(256)
        float alpha[4];
        #pragma unroll
        for (int r = 0; r < 4; ++r) {
            float mx = fmaxf(fmaxf(s[0][r], s[1][r]), fmaxf(s[2][r], s[3][r])) * scale;
            #pragma unroll
            for (int off = 1; off < 16; off <<= 1)
                mx = fmaxf(mx, __shfl_xor(mx, off, 64));
            float mnew = fmaxf(mrow[r], mx);
            alpha[r] = __expf(mrow[r] - mnew);  // -inf initial -> 0
            mrow[r] = mnew;
            float psum = 0.f;
            #pragma unroll
            for (int nf = 0; nf < 4; ++nf) {
                float p = __expf(s[nf][r] * scale - mnew);
                s[nf][r] = p;
                psum += p;
            }
            #pragma unroll
            for (int off = 1; off < 16; off <<= 1)
                psum += __shfl_xor(psum, off, 64);
            lsum[r] = lsum[r] * alpha[r] + psum;
        }

        // P -> LDS (bf16), per-wave region, no cross-wave sharing
        unsigned short* pbase = &lds_p[wave * 16 * LDP];
        #pragma unroll
        for (int nf = 0; nf < 4; ++nf) {
            #pragma unroll
            for (int r = 0; r < 4; ++r)
                pbase[(lkq * 4 + r) * LDP + nf * 16 + lrow] = f2bf(s[nf][r]);
        }

        // rescale O
        #pragma unroll
        for (int nf = 0; nf < 16; ++nf) {
            #pragma unroll
            for (int r = 0; r < 4; ++r) o[nf][r] *= alpha[r];
        }

        // O += P @ V   (A = P[16x64] from LDS, B = V^T rows = channels)
        #pragma unroll
        for (int ks = 0; ks < 2; ++ks) {
            bf16x8 a = *reinterpret_cast<const bf16x8*>(&pbase[lrow * LDP + ks * 32 + lk]);
            #pragma unroll
            for (int nf = 0; nf < 16; ++nf) {
                bf16x8 b = *reinterpret_cast<const bf16x8*>(
                    &lds_v[(nf * 16 + lrow) * LDV + ks * 32 + lk]);
                o[nf] = __builtin_amdgcn_mfma_f32_16x16x32_bf16(a, b, o[nf], 0, 0, 0);
            }
        }
        __syncthreads();
    }

    // epilogue: O / l -> bf16 h
    #pragma unroll
    for (int nf = 0; nf < 16; ++nf) {
        #pragma unroll
        for (int r = 0; r < 4; ++r) {
            float v = o[nf][r] / lsum[r];
            hg[(qrow0 + lkq * 4 + r) * C_DIM + nf * 16 + lrow] = f2bf(v);
        }
    }
}

// ---------------- K3: out = LayerNorm(x + h @ Wo^T + bo) * gamma + beta ----------------
__global__ __launch_bounds__(256, 2)
void out_kernel(const unsigned short* __restrict__ hb, const unsigned short* __restrict__ wob,
                const float* __restrict__ bo, const float* __restrict__ xg,
                const float* __restrict__ gamma, const float* __restrict__ beta,
                float* __restrict__ outg)
{
    __shared__ __align__(16) unsigned short lds_h[64 * LDK];
    const int tid = threadIdx.x;
    const int rowbase = blockIdx.x * 64;

    #pragma unroll
    for (int i = 0; i < 8; ++i) {
        int e = i * 2048 + tid * 8;
        int r = e >> 8, c = e & 255;
        *reinterpret_cast<uint4*>(&lds_h[r * LDK + c]) =
            *reinterpret_cast<const uint4*>(hb + (size_t)(rowbase + r) * C_DIM + c);
    }
    __syncthreads();

    const int lane = tid & 63, wave = tid >> 6;
    const int lrow = lane & 15, lkq = lane >> 4, lk = lkq * 8;
    const int r0 = wave * 16;

    bf16x8 a[8];
    #pragma unroll
    for (int ks = 0; ks < 8; ++ks)
        a[ks] = *reinterpret_cast<const bf16x8*>(&lds_h[(r0 + lrow) * LDK + ks * 32 + lk]);

    f32x4 acc[16];
    #pragma unroll
    for (int nf = 0; nf < 16; ++nf) acc[nf] = f32x4{0.f, 0.f, 0.f, 0.f};

    #pragma unroll
    for (int nf = 0; nf < 16; ++nf) {
        const unsigned short* wrow = wob + (nf * 16 + lrow) * C_DIM + lk;
        #pragma unroll
        for (int ks = 0; ks < 8; ++ks) {
            bf16x8 b = *reinterpret_cast<const bf16x8*>(wrow + ks * 32);
            acc[nf] = __builtin_amdgcn_mfma_f32_16x16x32_bf16(a[ks], b, acc[nf], 0, 0, 0);
        }
    }

    // z = x + o + bo  (fp32)
    #pragma unroll
    for (int nf = 0; nf < 16; ++nf) {
        float bv = bo[nf * 16 + lrow];
        #pragma unroll
        for (int r = 0; r < 4; ++r) {
            size_t row = rowbase + r0 + lkq * 4 + r;
            acc[nf][r] += bv + xg[row * C_DIM + nf * 16 + lrow];
        }
    }

    // LayerNorm per row (256 elems spread over 16 lanes x 16 nf)
    float mu[4], rstd[4];
    #pragma unroll
    for (int r = 0; r < 4; ++r) {
        float s1 = 0.f, s2 = 0.f;
        #pragma unroll
        for (int nf = 0; nf < 16; ++nf) { float v = acc[nf][r]; s1 += v; s2 += v * v; }
        #pragma unroll
        for (int off = 1; off < 16; off <<= 1) {
            s1 += __shfl_xor(s1, off, 64);
            s2 += __shfl_xor(s2, off, 64);
        }
        float m = s1 * (1.f / 256.f);
        mu[r] = m;
        rstd[r] = rsqrtf(s2 * (1.f / 256.f) - m * m + 1e-5f);
    }

    #pragma unroll
    for (int nf = 0; nf < 16; ++nf) {
        float g = gamma[nf * 16 + lrow];
        float bt = beta[nf * 16 + lrow];
        #pragma unroll
        for (int r = 0; r < 4; ++r) {
            size_t row = rowbase + r0 + lkq * 4 + r;
            outg[row * C_DIM + nf * 16 + lrow] = (acc[nf][r] - mu[r]) * rstd[r] * g + bt;
        }
    }
}

extern "C" void kernel_launch(void* const* d_in, const int* in_sizes, int n_in,
                              void* d_out, int out_size, void* d_ws, size_t ws_size,
                              hipStream_t stream) {
    const float* x     = (const float*)d_in[0];
    const float* y     = (const float*)d_in[1];
    const float* Wq    = (const float*)d_in[2];
    const float* bq    = (const float*)d_in[3];
    const float* Wk    = (const float*)d_in[4];
    const float* bk    = (const float*)d_in[5];
    const float* Wv    = (const float*)d_in[6];
    const float* bv    = (const float*)d_in[7];
    const float* Wo    = (const float*)d_in[8];
    const float* bo    = (const float*)d_in[9];
    const float* gamma = (const float*)d_in[10];
    const float* beta  = (const float*)d_in[11];
    float* out = (float*)d_out;

    // workspace layout (bf16 = unsigned short), total ~64.5 MB
    unsigned short* wq_b = (unsigned short*)d_ws;
    unsigned short* wk_b = wq_b + 65536;
    unsigned short* wv_b = wk_b + 65536;
    unsigned short* wo_b = wv_b + 65536;
    unsigned short* q_b  = wo_b + 65536;
    unsigned short* k_b  = q_b + 8388608;
    unsigned short* vT_b = k_b + 8388608;
    unsigned short* h_b  = vT_b + 8388608;

    cvt_w_kernel<<<64, 256, 0, stream>>>(Wq, wq_b);
    cvt_w_kernel<<<64, 256, 0, stream>>>(Wk, wk_b);
    cvt_w_kernel<<<64, 256, 0, stream>>>(Wv, wv_b);
    cvt_w_kernel<<<64, 256, 0, stream>>>(Wo, wo_b);

    proj_kernel<0><<<512, 256, 0, stream>>>(x, wq_b, bq, q_b);
    proj_kernel<0><<<512, 256, 0, stream>>>(y, wk_b, bk, k_b);
    proj_kernel<1><<<512, 256, 0, stream>>>(y, wv_b, bv, vT_b);

    attn_kernel<<<256, 512, 0, stream>>>(q_b, k_b, vT_b, h_b);

    out_kernel<<<512, 256, 0, stream>>>(h_b, wo_b, bo, x, gamma, beta, out);
}

// Round 2
// 344.302 us; speedup vs baseline: 1.2676x; 1.2676x over previous
//
#include <hip/hip_runtime.h>
#include <hip/hip_bf16.h>

// Shapes fixed by the problem: B=8, M=N=4096, C=256.
#define C_DIM 256
#define LDK 264   // padded LDS row (bf16) for proj/out staging tiles
#define QSCALE 0.09016844f  // (1/sqrt(256)) * log2(e): softmax done in exp2 domain

typedef __attribute__((ext_vector_type(8))) short bf16x8;
typedef __attribute__((ext_vector_type(4))) float f32x4;
typedef __attribute__((ext_vector_type(16))) float f32x16;

__device__ __forceinline__ unsigned short f2bf(float f) {
    union { float f; unsigned u; } v; v.f = f;
    return (unsigned short)((v.u + 0x7fffu + ((v.u >> 16) & 1u)) >> 16);  // RNE
}

__device__ __forceinline__ void gload16(const unsigned short* g, unsigned short* l) {
    __builtin_amdgcn_global_load_lds(
        (const __attribute__((address_space(1))) void*)g,
        (__attribute__((address_space(3))) void*)l, 16, 0, 0);
}

// ---------------- K0: all 4 weights fp32 -> bf16, one launch ----------------
__global__ void cvt_w_kernel(const float* __restrict__ w0, const float* __restrict__ w1,
                             const float* __restrict__ w2, const float* __restrict__ w3,
                             unsigned short* __restrict__ o0, unsigned short* __restrict__ o1,
                             unsigned short* __restrict__ o2, unsigned short* __restrict__ o3) {
    int which = blockIdx.x >> 6;
    const float* w = which == 0 ? w0 : (which == 1 ? w1 : (which == 2 ? w2 : w3));
    unsigned short* o = which == 0 ? o0 : (which == 1 ? o1 : (which == 2 ? o2 : o3));
    int i = ((blockIdx.x & 63) * 256 + threadIdx.x) * 4;
    float4 v = *reinterpret_cast<const float4*>(w + i);
    ushort4 b;
    b.x = f2bf(v.x); b.y = f2bf(v.y); b.z = f2bf(v.z); b.w = f2bf(v.w);
    *reinterpret_cast<ushort4*>(o + i) = b;
}

// ---------------- K1: fused q/k/v projections, out = in @ W^T + b (bf16) ----------------
// which = bx>>9: 0 -> q (scaled by QSCALE, row-major), 1 -> k (row-major), 2 -> v (stored [B][C][N])
__global__ __launch_bounds__(256, 2)
void proj_kernel(const float* __restrict__ x, const float* __restrict__ y,
                 const unsigned short* __restrict__ wq, const unsigned short* __restrict__ wk,
                 const unsigned short* __restrict__ wv,
                 const float* __restrict__ bqp, const float* __restrict__ bkp,
                 const float* __restrict__ bvp,
                 unsigned short* __restrict__ qo, unsigned short* __restrict__ ko,
                 unsigned short* __restrict__ vo)
{
    __shared__ __align__(16) unsigned short lds_in[64 * LDK];
    const int which = blockIdx.x >> 9;
    const int tile = blockIdx.x & 511;
    const float* in = (which == 0) ? x : y;
    const unsigned short* wbf = (which == 0) ? wq : (which == 1 ? wk : wv);
    const float* bias = (which == 0) ? bqp : (which == 1 ? bkp : bvp);
    unsigned short* out = (which == 0) ? qo : (which == 1 ? ko : vo);
    const float oscale = (which == 0) ? QSCALE : 1.0f;

    const int tid = threadIdx.x;
    const int rowbase = tile * 64;

    #pragma unroll
    for (int i = 0; i < 16; ++i) {
        int e = i * 1024 + tid * 4;
        int r = e >> 8, c = e & 255;
        float4 v = *reinterpret_cast<const float4*>(in + (size_t)(rowbase + r) * C_DIM + c);
        ushort4 b;
        b.x = f2bf(v.x); b.y = f2bf(v.y); b.z = f2bf(v.z); b.w = f2bf(v.w);
        *reinterpret_cast<ushort4*>(&lds_in[r * LDK + c]) = b;
    }
    __syncthreads();

    const int lane = tid & 63, wave = tid >> 6;
    const int lrow = lane & 15, lkq = lane >> 4, lk = lkq * 8;
    const int r0 = wave * 16;

    bf16x8 a[8];
    #pragma unroll
    for (int ks = 0; ks < 8; ++ks)
        a[ks] = *reinterpret_cast<const bf16x8*>(&lds_in[(r0 + lrow) * LDK + ks * 32 + lk]);

    f32x4 acc[16];
    #pragma unroll
    for (int nf = 0; nf < 16; ++nf) acc[nf] = f32x4{0.f, 0.f, 0.f, 0.f};

    #pragma unroll
    for (int nf = 0; nf < 16; ++nf) {
        const unsigned short* wrow = wbf + (nf * 16 + lrow) * C_DIM + lk;
        #pragma unroll
        for (int ks = 0; ks < 8; ++ks) {
            bf16x8 b = *reinterpret_cast<const bf16x8*>(wrow + ks * 32);
            acc[nf] = __builtin_amdgcn_mfma_f32_16x16x32_bf16(a[ks], b, acc[nf], 0, 0, 0);
        }
    }

    if (which != 2) {
        #pragma unroll
        for (int nf = 0; nf < 16; ++nf) {
            float bv = bias[nf * 16 + lrow];
            #pragma unroll
            for (int r = 0; r < 4; ++r) {
                int row = rowbase + r0 + lkq * 4 + r;
                out[(size_t)row * C_DIM + nf * 16 + lrow] = f2bf((acc[nf][r] + bv) * oscale);
            }
        }
    } else {
        int grow = rowbase + r0 + lkq * 4;
        int bb = grow >> 12, n0 = grow & 4095;
        #pragma unroll
        for (int nf = 0; nf < 16; ++nf) {
            float bv = bias[nf * 16 + lrow];
            int c = nf * 16 + lrow;
            ushort4 pk;
            pk.x = f2bf(acc[nf][0] + bv);
            pk.y = f2bf(acc[nf][1] + bv);
            pk.z = f2bf(acc[nf][2] + bv);
            pk.w = f2bf(acc[nf][3] + bv);
            *reinterpret_cast<ushort4*>(out + ((size_t)(bb * C_DIM + c) << 12) + n0) = pk;
        }
    }
}

// ---------------- K2: flash attention, 32x32x16 MFMA, swapped QK^T, O^T accum ----------------
// grid 256: batch = bx&7 (one batch per XCD), mt = bx>>3. 256 thr = 4 waves x 32 q rows.
// LDS 128KB: K dbuf 2x[64][256] + V^T dbuf 2x[256][64], 16B-chunk XOR swizzle (chunk ^= row&7).
__global__ __launch_bounds__(256, 1)
void attn_kernel(const unsigned short* __restrict__ qg, const unsigned short* __restrict__ kg,
                 const unsigned short* __restrict__ vtg, unsigned short* __restrict__ hg)
{
    __shared__ __align__(16) unsigned short smem[65536];  // 128 KB

    const int tid = threadIdx.x;
    const int lane = tid & 63;
    const int w = tid >> 6;
    const int l31 = lane & 31;
    const int l7 = lane & 7;
    const int hi5 = lane >> 5;     // 0 or 1
    const int r3 = lane >> 3;      // 0..7

    const int batch = blockIdx.x & 7;
    const int mt = blockIdx.x >> 3;
    const size_t q0 = (size_t)batch * 4096 + mt * 128 + w * 32;

    const unsigned short* kbase = kg + (size_t)batch * 4096 * 256;
    const unsigned short* vbase = vtg + (size_t)batch * 256 * 4096;

    // Q fragments (QK^T B-operand): lane holds Q[q0+l31][16*ks + 8*hi5 + j], already scaled
    bf16x8 qf[16];
    #pragma unroll
    for (int ks = 0; ks < 16; ++ks)
        qf[ks] = *reinterpret_cast<const bf16x8*>(qg + (q0 + l31) * 256 + ks * 16 + hi5 * 8);

    // O^T accumulators: o[cb][reg] = O^T[c = 32cb + (reg&3)+8*(reg>>2)+4*hi5][q = q0 + l31]
    f32x16 o[8];
    #pragma unroll
    for (int cb = 0; cb < 8; ++cb) {
        #pragma unroll
        for (int r = 0; r < 16; ++r) o[cb][r] = 0.f;
    }

    float m_run = -__builtin_inff();
    float lsum = 0.f;

    // stage one KV tile (K [64][256], V^T [256][64]) into buffer `buf` via global_load_lds.
    // LDS layout is linear; the 16B-chunk swizzle (pos = chunk ^ (row&7)) is applied by
    // reading the swizzled *source* chunk for each linear LDS slot (m173 pattern).
    auto stage = [&](int buf, int kv0) {
        unsigned short* lk = smem + buf * 16384;
        unsigned short* lv = smem + 32768 + buf * 16384;
        #pragma unroll
        for (int i = 0; i < 8; ++i) {
            int g = w * 8 + i;               // 1KB group: rows {2g, 2g+1}
            int row = 2 * g + hi5;
            gload16(kbase + (size_t)(kv0 + row) * 256 + ((l31 ^ (row & 7)) << 3), lk + g * 512);
        }
        #pragma unroll
        for (int i = 0; i < 8; ++i) {
            int g = w * 8 + i;               // 1KB group: rows {8g .. 8g+7}
            int row = 8 * g + r3;
            gload16(vbase + (size_t)row * 4096 + kv0 + ((l7 ^ r3) << 3), lv + g * 512);
        }
    };

    stage(0, 0);
    __syncthreads();

    for (int kt = 0; kt < 64; ++kt) {
        const int cur = kt & 1;
        if (kt < 63) stage(cur ^ 1, (kt + 1) * 64);

        const unsigned short* kc = smem + cur * 16384;
        const unsigned short* vc = smem + 32768 + cur * 16384;

        // ---- S^T = K Q^T (scores already in log2 domain via QSCALE) ----
        f32x16 s0, s1;
        #pragma unroll
        for (int r = 0; r < 16; ++r) { s0[r] = 0.f; s1[r] = 0.f; }
        const unsigned short* krow = kc + l31 * 256;
        #pragma unroll
        for (int ks = 0; ks < 16; ++ks) {
            int off = ((2 * ks + hi5) ^ l7) << 3;
            bf16x8 a0 = *reinterpret_cast<const bf16x8*>(krow + off);
            s0 = __builtin_amdgcn_mfma_f32_32x32x16_bf16(a0, qf[ks], s0, 0, 0, 0);
            bf16x8 a1 = *reinterpret_cast<const bf16x8*>(krow + 8192 + off);
            s1 = __builtin_amdgcn_mfma_f32_32x32x16_bf16(a1, qf[ks], s1, 0, 0, 0);
        }

        // ---- online softmax, lane-local (q = l31; kv split across hi halves) ----
        float mloc = s0[0];
        #pragma unroll
        for (int r = 1; r < 16; ++r) mloc = fmaxf(mloc, s0[r]);
        #pragma unroll
        for (int r = 0; r < 16; ++r) mloc = fmaxf(mloc, s1[r]);
        mloc = fmaxf(mloc, __shfl_xor(mloc, 32, 64));

        if (__any(mloc > m_run + 8.0f)) {   // defer-max (T13), log2 units
            float mn = fmaxf(m_run, mloc);
            float al = exp2f(m_run - mn);
            m_run = mn;
            lsum *= al;
            #pragma unroll
            for (int cb = 0; cb < 8; ++cb) {
                #pragma unroll
                for (int r = 0; r < 16; ++r) o[cb][r] *= al;
            }
        }

        float ts = 0.f;
        #pragma unroll
        for (int r = 0; r < 16; ++r) { s0[r] = exp2f(s0[r] - m_run); ts += s0[r]; }
        #pragma unroll
        for (int r = 0; r < 16; ++r) { s1[r] = exp2f(s1[r] - m_run); ts += s1[r]; }
        ts += __shfl_xor(ts, 32, 64);
        lsum += ts;

        // ---- pack P to bf16 pairs: Wu[kb][j] holds kv = 32kb + 8*(j>>1) + 2*(j&1) + 4*hi5, +1 ----
        unsigned Wu[2][8];
        #pragma unroll
        for (int j = 0; j < 8; ++j) {
            const int r = 4 * (j >> 1) + 2 * (j & 1);
            float a0 = s0[r], b0 = s0[r + 1], a1 = s1[r], b1 = s1[r + 1];
            asm("v_cvt_pk_bf16_f32 %0, %1, %2" : "=v"(Wu[0][j]) : "v"(a0), "v"(b0));
            asm("v_cvt_pk_bf16_f32 %0, %1, %2" : "=v"(Wu[1][j]) : "v"(a1), "v"(b1));
        }

        // ---- redistribute to PV B-fragments: pw[ks][t] = P^T word at kv = 16ks + 8hi + 2t ----
        unsigned pw[4][4];
        const bool h = (hi5 != 0);
        #pragma unroll
        for (int kb = 0; kb < 2; ++kb) {
            #pragma unroll
            for (int b4 = 0; b4 < 2; ++b4) {
                #pragma unroll
                for (int b = 0; b < 2; ++b) {
                    unsigned wlo = Wu[kb][4 * b4 + b];        // a even
                    unsigned whi = Wu[kb][4 * b4 + 2 + b];    // a odd
                    unsigned snd = h ? wlo : whi;             // send what partner half needs
                    unsigned rcv = __shfl_xor(snd, 32, 64);
                    unsigned own = h ? whi : wlo;             // keep what this half needs
                    const int ks = 2 * kb + b4;
                    pw[ks][b]     = h ? rcv : own;
                    pw[ks][2 + b] = h ? own : rcv;
                }
            }
        }

        // ---- O^T += V^T P^T ----
        #pragma unroll
        for (int ksv = 0; ksv < 4; ++ksv) {
            union { unsigned u[4]; bf16x8 v; } pb;
            pb.u[0] = pw[ksv][0]; pb.u[1] = pw[ksv][1];
            pb.u[2] = pw[ksv][2]; pb.u[3] = pw[ksv][3];
            int voff = ((2 * ksv + hi5) ^ l7) << 3;
            #pragma unroll
            for (int cb = 0; cb < 8; ++cb) {
                bf16x8 vf = *reinterpret_cast<const bf16x8*>(vc + (cb * 32 + l31) * 64 + voff);
                o[cb] = __builtin_amdgcn_mfma_f32_32x32x16_bf16(vf, pb.v, o[cb], 0, 0, 0);
            }
        }

        __syncthreads();   // staged tile for kt+1 drained (vmcnt 0) + everyone done with cur
    }

    // ---- epilogue: O^T / lsum -> transpose via per-wave LDS region -> coalesced h stores ----
    float rinv = 1.0f / lsum;
    unsigned short* tr = smem + w * 4096;   // 32 rows x 72 shorts used
    #pragma unroll
    for (int cc = 0; cc < 4; ++cc) {
        #pragma unroll
        for (int cbh = 0; cbh < 2; ++cbh) {
            const int cb = cc * 2 + cbh;
            #pragma unroll
            for (int rp = 0; rp < 8; ++rp) {
                const int r = 2 * rp;
                float lo = o[cb][r] * rinv, hi_ = o[cb][r + 1] * rinv;
                unsigned wpk;
                asm("v_cvt_pk_bf16_f32 %0, %1, %2" : "=v"(wpk) : "v"(lo), "v"(hi_));
                int c_local = 32 * cbh + (r & 3) + 8 * (r >> 2) + 4 * hi5;
                *reinterpret_cast<unsigned*>(tr + l31 * 72 + c_local) = wpk;
            }
        }
        __builtin_amdgcn_s_waitcnt(0);  // lgkmcnt(0): same-wave LDS RAW
        #pragma unroll
        for (int i = 0; i < 4; ++i) {
            int idx = i * 64 + lane;
            int q = idx >> 3, ch = idx & 7;
            uint4 d = *reinterpret_cast<const uint4*>(tr + q * 72 + ch * 8);
            *reinterpret_cast<uint4*>(hg + (q0 + q) * 256 + cc * 64 + ch * 8) = d;
        }
    }
}

// ---------------- K3: out = LayerNorm(x + h @ Wo^T + bo) * gamma + beta ----------------
__global__ __launch_bounds__(256, 2)
void out_kernel(const unsigned short* __restrict__ hb, const unsigned short* __restrict__ wob,
                const float* __restrict__ bo, const float* __restrict__ xg,
                const float* __restrict__ gamma, const float* __restrict__ beta,
                float* __restrict__ outg)
{
    __shared__ __align__(16) unsigned short lds_h[64 * LDK];
    const int tid = threadIdx.x;
    const int rowbase = blockIdx.x * 64;

    #pragma unroll
    for (int i = 0; i < 8; ++i) {
        int e = i * 2048 + tid * 8;
        int r = e >> 8, c = e & 255;
        *reinterpret_cast<uint4*>(&lds_h[r * LDK + c]) =
            *reinterpret_cast<const uint4*>(hb + (size_t)(rowbase + r) * C_DIM + c);
    }
    __syncthreads();

    const int lane = tid & 63, wave = tid >> 6;
    const int lrow = lane & 15, lkq = lane >> 4, lk = lkq * 8;
    const int r0 = wave * 16;

    bf16x8 a[8];
    #pragma unroll
    for (int ks = 0; ks < 8; ++ks)
        a[ks] = *reinterpret_cast<const bf16x8*>(&lds_h[(r0 + lrow) * LDK + ks * 32 + lk]);

    f32x4 acc[16];
    #pragma unroll
    for (int nf = 0; nf < 16; ++nf) acc[nf] = f32x4{0.f, 0.f, 0.f, 0.f};

    #pragma unroll
    for (int nf = 0; nf < 16; ++nf) {
        const unsigned short* wrow = wob + (nf * 16 + lrow) * C_DIM + lk;
        #pragma unroll
        for (int ks = 0; ks < 8; ++ks) {
            bf16x8 b = *reinterpret_cast<const bf16x8*>(wrow + ks * 32);
            acc[nf] = __builtin_amdgcn_mfma_f32_16x16x32_bf16(a[ks], b, acc[nf], 0, 0, 0);
        }
    }

    #pragma unroll
    for (int nf = 0; nf < 16; ++nf) {
        float bv = bo[nf * 16 + lrow];
        #pragma unroll
        for (int r = 0; r < 4; ++r) {
            size_t row = rowbase + r0 + lkq * 4 + r;
            acc[nf][r] += bv + xg[row * C_DIM + nf * 16 + lrow];
        }
    }

    float mu[4], rstd[4];
    #pragma unroll
    for (int r = 0; r < 4; ++r) {
        float s1 = 0.f, s2 = 0.f;
        #pragma unroll
        for (int nf = 0; nf < 16; ++nf) { float v = acc[nf][r]; s1 += v; s2 += v * v; }
        #pragma unroll
        for (int off = 1; off < 16; off <<= 1) {
            s1 += __shfl_xor(s1, off, 64);
            s2 += __shfl_xor(s2, off, 64);
        }
        float m = s1 * (1.f / 256.f);
        mu[r] = m;
        rstd[r] = rsqrtf(s2 * (1.f / 256.f) - m * m + 1e-5f);
    }

    #pragma unroll
    for (int nf = 0; nf < 16; ++nf) {
        float g = gamma[nf * 16 + lrow];
        float bt = beta[nf * 16 + lrow];
        #pragma unroll
        for (int r = 0; r < 4; ++r) {
            size_t row = rowbase + r0 + lkq * 4 + r;
            outg[row * C_DIM + nf * 16 + lrow] = (acc[nf][r] - mu[r]) * rstd[r] * g + bt;
        }
    }
}

extern "C" void kernel_launch(void* const* d_in, const int* in_sizes, int n_in,
                              void* d_out, int out_size, void* d_ws, size_t ws_size,
                              hipStream_t stream) {
    const float* x     = (const float*)d_in[0];
    const float* y     = (const float*)d_in[1];
    const float* Wq    = (const float*)d_in[2];
    const float* bq    = (const float*)d_in[3];
    const float* Wk    = (const float*)d_in[4];
    const float* bk    = (const float*)d_in[5];
    const float* Wv    = (const float*)d_in[6];
    const float* bv    = (const float*)d_in[7];
    const float* Wo    = (const float*)d_in[8];
    const float* bo    = (const float*)d_in[9];
    const float* gamma = (const float*)d_in[10];
    const float* beta  = (const float*)d_in[11];
    float* out = (float*)d_out;

    unsigned short* wq_b = (unsigned short*)d_ws;
    unsigned short* wk_b = wq_b + 65536;
    unsigned short* wv_b = wk_b + 65536;
    unsigned short* wo_b = wv_b + 65536;
    unsigned short* q_b  = wo_b + 65536;
    unsigned short* k_b  = q_b + 8388608;
    unsigned short* vT_b = k_b + 8388608;
    unsigned short* h_b  = vT_b + 8388608;

    cvt_w_kernel<<<256, 256, 0, stream>>>(Wq, Wk, Wv, Wo, wq_b, wk_b, wv_b, wo_b);

    proj_kernel<<<1536, 256, 0, stream>>>(x, y, wq_b, wk_b, wv_b, bq, bk, bv, q_b, k_b, vT_b);

    attn_kernel<<<256, 256, 0, stream>>>(q_b, k_b, vT_b, h_b);

    out_kernel<<<512, 256, 0, stream>>>(h_b, wo_b, bo, x, gamma, beta, out);
}